// Round 8
// baseline (214.524 us; speedup 1.0000x reference)
//
#include <hip/hip_runtime.h>
#include <math.h>

#define B_    8
#define N_    1024
#define FIN   512
#define FOUT  256
#define H_    8
#define ALPHA 0.2f

#define XT (B_ * N_ * FIN)     // 4194304 x elements
#define WT (H_ * FOUT * FIN)   // 1048576 W elements

typedef short s16x8 __attribute__((ext_vector_type(8)));
typedef float f32x4 __attribute__((ext_vector_type(4)));

__device__ __forceinline__ unsigned short f2bf(float f) {
  unsigned int u = __float_as_uint(f);
  u = (u + 0x7FFFu + ((u >> 16) & 1u)) >> 16;   // round-to-nearest-even
  return (unsigned short)u;
}

// pack 4 fp32 -> 4 OCP e4m3 bytes (v_cvt_pk_fp8_f32; OCP format on gfx950)
__device__ __forceinline__ unsigned int pk4_fp8(float a, float b, float c,
                                                float d) {
  int u = __builtin_amdgcn_cvt_pk_fp8_f32(a, b, 0, false);   // bytes 0,1
  u = __builtin_amdgcn_cvt_pk_fp8_f32(c, d, u, true);        // bytes 2,3
  return (unsigned int)u;
}

// Exact dequant-sum of 4 packed e4m3 bytes (bit-exact with what the MFMA
// consumes, summed in fp32).
#if __has_builtin(__builtin_amdgcn_cvt_pk_f32_fp8)
#define HAVE_DEQ4 1
__device__ __forceinline__ float deq4(unsigned int u) {
  const auto a = __builtin_amdgcn_cvt_pk_f32_fp8((int)u, false);
  const auto b = __builtin_amdgcn_cvt_pk_f32_fp8((int)u, true);
  return (a[0] + a[1]) + (b[0] + b[1]);
}
#else
#define HAVE_DEQ4 0
// Emulated e4m3 quantize (RNE); p is known to be in [0,1].
__device__ __forceinline__ float q8e4m3(float p) {
  if (p >= 0.015625f) {                      // normal range: 3 mantissa bits
    unsigned int u = __float_as_uint(p);
    u = (u + 0x7FFFFu + ((u >> 20) & 1u)) & 0xFFF00000u;
    return __uint_as_float(u);
  }
  return (p + 16384.f) - 16384.f;            // subnormal: snap to 2^-9 grid
}
#endif

// async global->LDS, 16 B per lane (global_load_lds_dwordx4)
__device__ __forceinline__ void gload16(const void* g, void* l) {
  __builtin_amdgcn_global_load_lds(
      (const __attribute__((address_space(1))) unsigned int*)g,
      (__attribute__((address_space(3))) unsigned int*)l, 16, 0, 0);
}

// generate 8 softmax weights -> 8 packed e4m3 bytes (A-fragment long) and
// accumulate their exact dequantized sum into dsum. Identical math to the
// old wgen kernel (leaky -> exp(l - mhat) -> adjacency mask -> pk4_fp8).
__device__ __forceinline__ long gen8(unsigned int ab, const float4 fA,
                                     const float4 fB, float f1i, float mhat,
                                     float& dsum) {
  float ex[8];
#pragma unroll
  for (int j = 0; j < 8; ++j) {
    const float fv = j < 4 ? ((const float*)&fA)[j] : ((const float*)&fB)[j - 4];
    const float tt = f1i + fv;
    const float l = fmaxf(tt, ALPHA * tt);
    const float p = __expf(l - mhat);
    ex[j] = ((ab >> j) & 1u) ? p : 0.f;
  }
  const unsigned int lo = pk4_fp8(ex[0], ex[1], ex[2], ex[3]);
  const unsigned int hi = pk4_fp8(ex[4], ex[5], ex[6], ex[7]);
#if HAVE_DEQ4
  dsum += deq4(lo) + deq4(hi);
#else
#pragma unroll
  for (int j = 0; j < 8; ++j) dsum += q8e4m3(ex[j]);
#endif
  return (long)(((unsigned long long)hi << 32) | (unsigned long long)lo);
}

// ---------------------------------------------------------------------------
// Fragment layouts (lane-linear, 512 B per (tile,kk) block):
//  htq (B-operand): block ((hb*16 + otg)*32 + kk), byte quad*128+col*8+j =
//      h[hb][k=kk*32+quad*8+j][o=otg*16+col]
//  A-operand (generated in-register): lane (col,quad) byte j =
//      softmax-weight[row=rb*16+col][k=kk*32+quad*8+j]
// ---------------------------------------------------------------------------

// ---------------------------------------------------------------------------
// Kernel 0: fp32->bf16 convert of x,W + zero f1/f2 + byte-transposed adj
// pack. adjP per row (128 B): byte [q*32 + kk] = adj bits j = kk*32+q*8 ..+7
// ---------------------------------------------------------------------------
#define CVB  ((XT + WT) / 1024)          // 5120 convert blocks
#define ZRB  128                         // zero blocks: f1,f2 (512 KB)
#define PKB  ((B_ * N_ * 32) / 256)      // 1024 adj-pack blocks

__global__ __launch_bounds__(256) void prep(
    const float* __restrict__ x, const float* __restrict__ W,
    const int* __restrict__ adj, unsigned short* __restrict__ xb,
    unsigned short* __restrict__ Wb, float* __restrict__ f12,
    unsigned int* __restrict__ adjP) {
  const int blk = blockIdx.x;
  if (blk >= CVB + ZRB) {    // ---- pack adj (byte-transposed) ----
    const int dw = (blk - CVB - ZRB) * 256 + threadIdx.x;  // permuted dword
    const int r = dw >> 5, pd = dw & 31;
    const int q = pd >> 3, c8 = pd & 7;                    // c8 = kk>>2
    const int* ap = adj + (size_t)r * N_;
    unsigned int out = 0;
#pragma unroll
    for (int i = 0; i < 4; ++i) {        // byte i: kk = c8*4+i
      const int jb = (c8 * 4 + i) * 32 + q * 8;
      int4 v0 = *(const int4*)(ap + jb);
      int4 v1 = *(const int4*)(ap + jb + 4);
      unsigned int byte = 0;
      byte |= (v0.x ? 1u : 0u) << 0; byte |= (v0.y ? 1u : 0u) << 1;
      byte |= (v0.z ? 1u : 0u) << 2; byte |= (v0.w ? 1u : 0u) << 3;
      byte |= (v1.x ? 1u : 0u) << 4; byte |= (v1.y ? 1u : 0u) << 5;
      byte |= (v1.z ? 1u : 0u) << 6; byte |= (v1.w ? 1u : 0u) << 7;
      out |= byte << (i * 8);
    }
    adjP[dw] = out;
    return;
  }
  if (blk >= CVB) {          // ---- zero f1/f2 (contiguous) ----
    const int i = (blk - CVB) * 256 + threadIdx.x;
    ((float4*)f12)[i] = make_float4(0.f, 0.f, 0.f, 0.f);
    return;
  }
  // ---- fp32 -> bf16 ----
  const int i = (blk * 256 + threadIdx.x) * 4;
  const float* src;
  unsigned short* dst;
  int off;
  if (i < XT) { src = x; dst = xb; off = i; }
  else        { src = W; dst = Wb; off = i - XT; }
  float4 v = *(const float4*)(src + off);
  ushort4 s;
  s.x = f2bf(v.x); s.y = f2bf(v.y); s.z = f2bf(v.z); s.w = f2bf(v.w);
  *(ushort4*)(dst + off) = s;
}

// ---------------------------------------------------------------------------
// Kernel 1: projection GEMM (unchanged): global_load_lds width=16 staging
// with pre-swizzled source, 128x128 tile, grid 1024.
// ---------------------------------------------------------------------------
__global__ __launch_bounds__(256, 3) void proj_mfma(
    const unsigned short* __restrict__ xb, const unsigned short* __restrict__ Wb,
    const float* __restrict__ a1, const float* __restrict__ a2,
    unsigned char* __restrict__ htq, float* __restrict__ f1,
    float* __restrict__ f2) {
  __shared__ __align__(16) unsigned short As[128 * 64];  // 16 KB
  __shared__ __align__(16) unsigned short Bs[128 * 64];  // 16 KB
  const int gid = blockIdx.x;
  const int b = gid & 7;
  const int mt_ = (gid >> 3) & 7;
  const int ot_ = (gid >> 6) & 1;
  const int h = gid >> 7;
  const int hb = h * B_ + b;
  const int m0 = mt_ * 128, o0 = ot_ * 128;
  const int t = threadIdx.x, w = t >> 6, lane = t & 63;
  const int col = lane & 15, quad = lane >> 4;

  const int srow = t >> 3;                       // 0..31
  const int sseg = (t & 7) ^ (srow & 7);
  const unsigned short* agp = xb + (size_t)(b * N_ + m0 + srow) * FIN + sseg * 8;
  const unsigned short* bgp = Wb + (size_t)(h * FOUT + o0 + srow) * FIN + sseg * 8;

  f32x4 acc[2][8];
  const f32x4 z4 = {0.f, 0.f, 0.f, 0.f};
#pragma unroll
  for (int mt = 0; mt < 2; ++mt)
#pragma unroll
    for (int ot = 0; ot < 8; ++ot) acc[mt][ot] = z4;

  for (int it = 0; it < FIN / 64; ++it) {
    __syncthreads();   // WAR: all waves done reading previous chunk
    const int k0 = it * 64;
#pragma unroll
    for (int i2 = 0; i2 < 4; ++i2) {
      gload16(agp + (size_t)i2 * 32 * FIN + k0, &As[i2 * 2048 + t * 8]);
      gload16(bgp + (size_t)i2 * 32 * FIN + k0, &Bs[i2 * 2048 + t * 8]);
    }
    __syncthreads();   // compiler drains vmcnt(0) before barrier -> data ready

#pragma unroll
    for (int kb = 0; kb < 2; ++kb) {
      s16x8 af[2], bf[8];
#pragma unroll
      for (int mt = 0; mt < 2; ++mt) {
        const int row = w * 32 + mt * 16 + col;
        af[mt] = *(const s16x8*)&As[row * 64 + ((kb * 4 + quad) ^ (row & 7)) * 8];
      }
#pragma unroll
      for (int ot = 0; ot < 8; ++ot) {
        const int row = ot * 16 + col;
        bf[ot] = *(const s16x8*)&Bs[row * 64 + ((kb * 4 + quad) ^ (row & 7)) * 8];
      }
#pragma unroll
      for (int mt = 0; mt < 2; ++mt)
#pragma unroll
        for (int ot = 0; ot < 8; ++ot)
          acc[mt][ot] = __builtin_amdgcn_mfma_f32_16x16x32_bf16(af[mt], bf[ot],
                                                                acc[mt][ot], 0, 0, 0);
    }
  }

  const int kkw = (m0 >> 5) + w;
  float pf1[2][4] = {{0.f}}, pf2[2][4] = {{0.f}};
#pragma unroll
  for (int mt = 0; mt < 2; ++mt) {
#pragma unroll
    for (int ot = 0; ot < 8; ++ot) {
      const int o = o0 + ot * 16 + col;
      const float va1 = a1[h * FOUT + o], va2 = a2[h * FOUT + o];
      const int otg = (o0 >> 4) + ot;
      unsigned char* fb =
          htq + (((size_t)(hb * 16 + otg) * 32 + kkw) << 9);
      const unsigned int q =
          pk4_fp8(acc[mt][ot][0], acc[mt][ot][1], acc[mt][ot][2], acc[mt][ot][3]);
      *(unsigned int*)(fb + (2 * mt + (quad >> 1)) * 128 + col * 8 +
                       (quad & 1) * 4) = q;
#pragma unroll
      for (int r = 0; r < 4; ++r) {
        pf1[mt][r] += acc[mt][ot][r] * va1;
        pf2[mt][r] += acc[mt][ot][r] * va2;
      }
    }
  }
#pragma unroll
  for (int off = 1; off <= 8; off <<= 1)
#pragma unroll
    for (int mt = 0; mt < 2; ++mt)
#pragma unroll
      for (int r = 0; r < 4; ++r) {
        pf1[mt][r] += __shfl_xor(pf1[mt][r], off);
        pf2[mt][r] += __shfl_xor(pf2[mt][r], off);
      }
  if (col == 0) {
#pragma unroll
    for (int mt = 0; mt < 2; ++mt)
#pragma unroll
      for (int r = 0; r < 4; ++r) {
        const int n = m0 + w * 32 + mt * 16 + quad * 4 + r;
        atomicAdd(&f1[hb * N_ + n], pf1[mt][r]);
        atomicAdd(&f2[hb * N_ + n], pf2[mt][r]);
      }
  }
}

// ---------------------------------------------------------------------------
// Kernel 2: pv — FUSED weight-gen + fp8 MFMA GEMM (wgen kernel deleted; the
// 64 MB wq round-trip is gone). Block = single head, 128 rows x 128 cols,
// 256 threads = 4 row-waves (wave = 32 rows x 128 cols, acc[2][8]).
// Grid 1024 = 8b(XCD) x 2oc x 8h x 8it -> 4 independent blocks/CU.
// Per phase (8 phases, 4 kk each): {stage next B-chunk (4 gload16) + next
// adj dwords (2)} -> {generate A-fragments in-register: exp/leaky/mask ->
// pk4_fp8 (bit-identical to old wgen) + inline deq4 denominator} -> 64 MFMA
// -> vmcnt(2) + raw barrier (stage retired, adj flies across).
// Denominator: after the 8 phases each lane holds its quad-slice row sum;
// 2 shfl_xor + shfl give the exact full-row quantized sums (no dnm array).
// ---------------------------------------------------------------------------
__global__ __launch_bounds__(256, 4) void pv(
    const unsigned char* __restrict__ htq, const float* __restrict__ f1,
    const float* __restrict__ f2, const unsigned int* __restrict__ adjP,
    float* __restrict__ pp) {
  __shared__ __align__(16) unsigned char Bsh[2][16384];  // [buf][otgl*2048+kkl*512]
  __shared__ __align__(16) float f2sh[N_];               // 4 KB, this head's f2
  const int id = blockIdx.x;
  const int b = id & 7;                // XCD-keyed
  const int oc = (id >> 3) & 1;        // col half: otg in [oc*8, +8)
  const int h = (id >> 4) & 7;         // single head
  const int it = id >> 7;              // 0..7 (128-row groups)
  const int tid = threadIdx.x;
  const int w = tid >> 6, lane = tid & 63;
  const int col = lane & 15, quad = lane >> 4;
  const int rb = it * 8 + w * 2;       // this wave's rows [rb*16, rb*16+32)

  const int hb = h * B_ + b;
  const unsigned char* bp = htq + (((size_t)(hb * 16 + oc * 8) * 32) << 9);
  const int row0 = rb * 16 + col;
  const int row1 = row0 + 16;
  const unsigned int* adp0 = adjP + ((size_t)(b * N_ + row0) << 5) + quad * 8;
  const unsigned int* adp1 = adjP + ((size_t)(b * N_ + row1) << 5) + quad * 8;

  // stage: 4 x gload16 per thread covers the 16 KB chunk (8 otgl x 2 KB).
  // flat = otgl*2048 + kkl*512 + byte ; global = bp + otgl*16384 + c*2048 + rest
#define STAGE(buf, c)                                                        \
  {                                                                          \
    _Pragma("unroll")                                                        \
    for (int i = 0; i < 4; ++i) {                                            \
      const int flat = i * 4096 + tid * 16;                                  \
      gload16(bp + (size_t)(flat >> 11) * 16384 + (c) * 2048 + (flat & 2047),\
              &Bsh[buf][flat]);                                              \
    }                                                                        \
  }

  f32x4 acc[2][8];
  const f32x4 z4 = {0.f, 0.f, 0.f, 0.f};
#pragma unroll
  for (int g = 0; g < 2; ++g)
#pragma unroll
    for (int t = 0; t < 8; ++t) acc[g][t] = z4;

  // ---- prologue: f2 -> LDS (4 KB), m2, f1, mhat, stage chunk0, adj0
  const float* f2r = f2 + (size_t)hb * N_;
  gload16(f2r + tid * 4, &f2sh[tid * 4]);
  STAGE(0, 0)
  float m2 = -3.0e38f;
#pragma unroll
  for (int c = 0; c < 16; ++c) m2 = fmaxf(m2, f2r[lane + c * 64]);
#pragma unroll
  for (int off = 32; off; off >>= 1) m2 = fmaxf(m2, __shfl_xor(m2, off));
  const float f1a = f1[(size_t)hb * N_ + row0];
  const float f1b = f1[(size_t)hb * N_ + row1];
  const float tb0 = f1a + m2, tb1 = f1b + m2;
  const float mh0 = fmaxf(tb0, ALPHA * tb0);   // >= leaky(f1a+f2j) for all j
  const float mh1 = fmaxf(tb1, ALPHA * tb1);
  unsigned int adA0 = adp0[0], adA1 = adp1[0];
  unsigned int adB0, adB1;
  float dsum0 = 0.f, dsum1 = 0.f;
  asm volatile("s_waitcnt vmcnt(0)" ::: "memory");
  __builtin_amdgcn_s_barrier();

#define PHASE(c, ADC0, ADC1, ADN0, ADN1)                                     \
  {                                                                          \
    if ((c) < 7) {                                                           \
      STAGE(1 - ((c) & 1), (c) + 1)                                          \
      ADN0 = adp0[(c) + 1];                                                  \
      ADN1 = adp1[(c) + 1];                                                  \
    }                                                                        \
    _Pragma("unroll")                                                        \
    for (int kkl = 0; kkl < 4; ++kkl) {                                      \
      const int kk = (c) * 4 + kkl;                                          \
      const float4 fA = *(const float4*)&f2sh[kk * 32 + quad * 8];           \
      const float4 fB = *(const float4*)&f2sh[kk * 32 + quad * 8 + 4];       \
      const long af0 =                                                       \
          gen8((ADC0 >> (kkl * 8)) & 0xFFu, fA, fB, f1a, mh0, dsum0);        \
      const long af1 =                                                       \
          gen8((ADC1 >> (kkl * 8)) & 0xFFu, fA, fB, f1b, mh1, dsum1);        \
      const unsigned char* bl_ = &Bsh[(c) & 1][kkl * 512 + lane * 8];        \
      __builtin_amdgcn_s_setprio(1);                                         \
      _Pragma("unroll")                                                      \
      for (int t = 0; t < 8; ++t) {                                          \
        const long bf = *(const long*)(bl_ + t * 2048);                      \
        acc[0][t] = __builtin_amdgcn_mfma_f32_16x16x32_fp8_fp8(af0, bf, acc[0][t], 0, 0, 0); \
        acc[1][t] = __builtin_amdgcn_mfma_f32_16x16x32_fp8_fp8(af1, bf, acc[1][t], 0, 0, 0); \
      }                                                                      \
      __builtin_amdgcn_s_setprio(0);                                         \
    }                                                                        \
    if ((c) < 7) {                                                           \
      asm volatile("s_waitcnt vmcnt(2)" ::: "memory"); /* stage retired */   \
      __builtin_amdgcn_s_barrier();                    /* adj flies */       \
    }                                                                        \
  }

  PHASE(0, adA0, adA1, adB0, adB1)
  PHASE(1, adB0, adB1, adA0, adA1)
  PHASE(2, adA0, adA1, adB0, adB1)
  PHASE(3, adB0, adB1, adA0, adA1)
  PHASE(4, adA0, adA1, adB0, adB1)
  PHASE(5, adB0, adB1, adA0, adA1)
  PHASE(6, adA0, adA1, adB0, adB1)
  PHASE(7, adB0, adB1, adA0, adA1)
#undef PHASE
#undef STAGE

  // ---- exact full-row denominators: quad-slices -> full sum per col
  dsum0 += __shfl_xor(dsum0, 16);
  dsum0 += __shfl_xor(dsum0, 32);
  dsum1 += __shfl_xor(dsum1, 16);
  dsum1 += __shfl_xor(dsum1, 32);

  // ---- normalize, ELU, write single-head partial
  float* pdst = pp + (size_t)h * ((size_t)B_ * N_ * FOUT);
#pragma unroll
  for (int g = 0; g < 2; ++g)
#pragma unroll
    for (int r = 0; r < 4; ++r) {
      const float den = __shfl(g == 0 ? dsum0 : dsum1, quad * 4 + r);
      const float inv = 1.0f / den;
      const int orow = (rb + g) * 16 + quad * 4 + r;
#pragma unroll
      for (int t = 0; t < 8; ++t) {
        const float oh = acc[g][t][r] * inv;
        pdst[(size_t)(b * N_ + orow) * FOUT + oc * 128 + t * 16 + col] =
            oh > 0.f ? oh : __expf(oh) - 1.f;
      }
    }
}

// ---------------------------------------------------------------------------
// Kernel 3: sum 8 single-head partials + log_softmax over o. Wave per row.
// ---------------------------------------------------------------------------
__global__ __launch_bounds__(256) void logsm(
    const float* __restrict__ pp, float* __restrict__ out) {
  const int row = blockIdx.x * 4 + (threadIdx.x >> 6);
  const int lane = threadIdx.x & 63;
  const size_t base = (size_t)row * FOUT;
  const size_t PSZ = (size_t)B_ * N_ * FOUT;
  float v[4];
  float m = -3.0e38f;
#pragma unroll
  for (int c = 0; c < 4; ++c) {
    const size_t idx = base + c * 64 + lane;
    float s = 0.f;
#pragma unroll
    for (int hh = 0; hh < 8; ++hh) s += pp[hh * PSZ + idx];
    v[c] = s;
    m = fmaxf(m, v[c]);
  }
#pragma unroll
  for (int off = 32; off; off >>= 1) m = fmaxf(m, __shfl_xor(m, off));
  float s = 0.f;
#pragma unroll
  for (int c = 0; c < 4; ++c) s += __expf(v[c] - m);
#pragma unroll
  for (int off = 32; off; off >>= 1) s += __shfl_xor(s, off);
  const float lg = m + logf(s);
#pragma unroll
  for (int c = 0; c < 4; ++c)
    out[base + c * 64 + lane] = v[c] - lg;
}

// ---------------------------------------------------------------------------
extern "C" void kernel_launch(void* const* d_in, const int* in_sizes, int n_in,
                              void* d_out, int out_size, void* d_ws,
                              size_t ws_size, hipStream_t stream) {
  const float* x   = (const float*)d_in[0];
  const int*   adj = (const int*)d_in[1];
  const float* W   = (const float*)d_in[2];
  const float* a1  = (const float*)d_in[3];
  const float* a2  = (const float*)d_in[4];
  float* out = (float*)d_out;

  unsigned char* htq = (unsigned char*)d_ws;                          // 16 MB fp8 h (frag)
  unsigned short* xb = (unsigned short*)(htq + (size_t)H_ * B_ * FOUT * N_); // 8 MB
  unsigned short* Wb = xb + (size_t)XT;                               // 2 MB
  float* f1 = (float*)(Wb + (size_t)WT);                              // 256 KB
  float* f2 = f1 + (size_t)H_ * B_ * N_;                              // 256 KB
  float* pad = f2 + (size_t)H_ * B_ * N_;                             // 256 KB (unused)
  float* part2 = pad + (size_t)H_ * B_ * N_;                          // 8 MB (unused)
  float* part3 = part2 + (size_t)B_ * N_ * FOUT;                      // 8 MB (unused)
  unsigned int* adjP = (unsigned int*)(part3 + (size_t)B_ * N_ * FOUT); // 1 MB
  float* pp = (float*)(adjP + (size_t)B_ * N_ * 32);  // 64 MB: 8 head partials

  prep<<<CVB + ZRB + PKB, 256, 0, stream>>>(x, W, adj, xb, Wb, f1, adjP);

  proj_mfma<<<1024, 256, 0, stream>>>(xb, Wb, a1, a2, htq, f1, f2);

  pv<<<1024, 256, 0, stream>>>(htq, f1, f2, adjP, pp);

  logsm<<<(B_ * N_) / 4, 256, 0, stream>>>(pp, out);
}

// Round 9
// 203.501 us; speedup vs baseline: 1.0542x; 1.0542x over previous
//
#include <hip/hip_runtime.h>
#include <math.h>

#define B_    8
#define N_    1024
#define FIN   512
#define FOUT  256
#define H_    8
#define ALPHA 0.2f

#define XT (B_ * N_ * FIN)     // 4194304 x elements
#define WT (H_ * FOUT * FIN)   // 1048576 W elements

typedef short s16x8 __attribute__((ext_vector_type(8)));
typedef float f32x4 __attribute__((ext_vector_type(4)));

__device__ __forceinline__ unsigned short f2bf(float f) {
  unsigned int u = __float_as_uint(f);
  u = (u + 0x7FFFu + ((u >> 16) & 1u)) >> 16;   // round-to-nearest-even
  return (unsigned short)u;
}

// pack 4 fp32 -> 4 OCP e4m3 bytes (v_cvt_pk_fp8_f32; OCP format on gfx950)
__device__ __forceinline__ unsigned int pk4_fp8(float a, float b, float c,
                                                float d) {
  int u = __builtin_amdgcn_cvt_pk_fp8_f32(a, b, 0, false);   // bytes 0,1
  u = __builtin_amdgcn_cvt_pk_fp8_f32(c, d, u, true);        // bytes 2,3
  return (unsigned int)u;
}

// Exact dequant-sum of 4 packed e4m3 bytes (bit-exact with what the MFMA
// consumes, summed in fp32).
#if __has_builtin(__builtin_amdgcn_cvt_pk_f32_fp8)
#define HAVE_DEQ4 1
__device__ __forceinline__ float deq4(unsigned int u) {
  const auto a = __builtin_amdgcn_cvt_pk_f32_fp8((int)u, false);
  const auto b = __builtin_amdgcn_cvt_pk_f32_fp8((int)u, true);
  return (a[0] + a[1]) + (b[0] + b[1]);
}
#else
#define HAVE_DEQ4 0
// Emulated e4m3 quantize (RNE); p is known to be in [0,1].
__device__ __forceinline__ float q8e4m3(float p) {
  if (p >= 0.015625f) {                      // normal range: 3 mantissa bits
    unsigned int u = __float_as_uint(p);
    u = (u + 0x7FFFFu + ((u >> 20) & 1u)) & 0xFFF00000u;
    return __uint_as_float(u);
  }
  return (p + 16384.f) - 16384.f;            // subnormal: snap to 2^-9 grid
}
#endif

// async global->LDS, 16 B per lane (global_load_lds_dwordx4)
__device__ __forceinline__ void gload16(const void* g, void* l) {
  __builtin_amdgcn_global_load_lds(
      (const __attribute__((address_space(1))) unsigned int*)g,
      (__attribute__((address_space(3))) unsigned int*)l, 16, 0, 0);
}

// generate 8 softmax weights -> 8 packed e4m3 bytes (A-fragment long) and
// accumulate their exact dequantized sum into dsum. Identical math to the
// old wgen kernel (leaky -> exp(l - mhat) -> adjacency mask -> pk4_fp8).
__device__ __forceinline__ long gen8(unsigned int ab, const float4 fA,
                                     const float4 fB, float f1i, float mhat,
                                     float& dsum) {
  float ex[8];
#pragma unroll
  for (int j = 0; j < 8; ++j) {
    const float fv = j < 4 ? ((const float*)&fA)[j] : ((const float*)&fB)[j - 4];
    const float tt = f1i + fv;
    const float l = fmaxf(tt, ALPHA * tt);
    const float p = __expf(l - mhat);
    ex[j] = ((ab >> j) & 1u) ? p : 0.f;
  }
  const unsigned int lo = pk4_fp8(ex[0], ex[1], ex[2], ex[3]);
  const unsigned int hi = pk4_fp8(ex[4], ex[5], ex[6], ex[7]);
#if HAVE_DEQ4
  dsum += deq4(lo) + deq4(hi);
#else
#pragma unroll
  for (int j = 0; j < 8; ++j) dsum += q8e4m3(ex[j]);
#endif
  return (long)(((unsigned long long)hi << 32) | (unsigned long long)lo);
}

// ---------------------------------------------------------------------------
// Fragment layouts (lane-linear, 512 B per (tile,kk) block):
//  htq (B-operand): block ((hb*16 + otg)*32 + kk), byte quad*128+col*8+j =
//      h[hb][k=kk*32+quad*8+j][o=otg*16+col]
//  A-operand (generated in-register): lane (col,quad) byte j =
//      softmax-weight[row=rb*16+col][k=kk*32+quad*8+j]
// ---------------------------------------------------------------------------

// ---------------------------------------------------------------------------
// Kernel 0: fp32->bf16 convert of x,W + zero f1/f2 + byte-transposed adj
// pack. adjP per row (128 B): byte [q*32 + kk] = adj bits j = kk*32+q*8 ..+7
// ---------------------------------------------------------------------------
#define CVB  ((XT + WT) / 1024)          // 5120 convert blocks
#define ZRB  128                         // zero blocks: f1,f2 (512 KB)
#define PKB  ((B_ * N_ * 32) / 256)      // 1024 adj-pack blocks

__global__ __launch_bounds__(256) void prep(
    const float* __restrict__ x, const float* __restrict__ W,
    const int* __restrict__ adj, unsigned short* __restrict__ xb,
    unsigned short* __restrict__ Wb, float* __restrict__ f12,
    unsigned int* __restrict__ adjP) {
  const int blk = blockIdx.x;
  if (blk >= CVB + ZRB) {    // ---- pack adj (byte-transposed) ----
    const int dw = (blk - CVB - ZRB) * 256 + threadIdx.x;  // permuted dword
    const int r = dw >> 5, pd = dw & 31;
    const int q = pd >> 3, c8 = pd & 7;                    // c8 = kk>>2
    const int* ap = adj + (size_t)r * N_;
    unsigned int out = 0;
#pragma unroll
    for (int i = 0; i < 4; ++i) {        // byte i: kk = c8*4+i
      const int jb = (c8 * 4 + i) * 32 + q * 8;
      int4 v0 = *(const int4*)(ap + jb);
      int4 v1 = *(const int4*)(ap + jb + 4);
      unsigned int byte = 0;
      byte |= (v0.x ? 1u : 0u) << 0; byte |= (v0.y ? 1u : 0u) << 1;
      byte |= (v0.z ? 1u : 0u) << 2; byte |= (v0.w ? 1u : 0u) << 3;
      byte |= (v1.x ? 1u : 0u) << 4; byte |= (v1.y ? 1u : 0u) << 5;
      byte |= (v1.z ? 1u : 0u) << 6; byte |= (v1.w ? 1u : 0u) << 7;
      out |= byte << (i * 8);
    }
    adjP[dw] = out;
    return;
  }
  if (blk >= CVB) {          // ---- zero f1/f2 (contiguous) ----
    const int i = (blk - CVB) * 256 + threadIdx.x;
    ((float4*)f12)[i] = make_float4(0.f, 0.f, 0.f, 0.f);
    return;
  }
  // ---- fp32 -> bf16 ----
  const int i = (blk * 256 + threadIdx.x) * 4;
  const float* src;
  unsigned short* dst;
  int off;
  if (i < XT) { src = x; dst = xb; off = i; }
  else        { src = W; dst = Wb; off = i - XT; }
  float4 v = *(const float4*)(src + off);
  ushort4 s;
  s.x = f2bf(v.x); s.y = f2bf(v.y); s.z = f2bf(v.z); s.w = f2bf(v.w);
  *(ushort4*)(dst + off) = s;
}

// ---------------------------------------------------------------------------
// Kernel 1: projection GEMM (unchanged): global_load_lds width=16 staging
// with pre-swizzled source, 128x128 tile, grid 1024.
// ---------------------------------------------------------------------------
__global__ __launch_bounds__(256, 3) void proj_mfma(
    const unsigned short* __restrict__ xb, const unsigned short* __restrict__ Wb,
    const float* __restrict__ a1, const float* __restrict__ a2,
    unsigned char* __restrict__ htq, float* __restrict__ f1,
    float* __restrict__ f2) {
  __shared__ __align__(16) unsigned short As[128 * 64];  // 16 KB
  __shared__ __align__(16) unsigned short Bs[128 * 64];  // 16 KB
  const int gid = blockIdx.x;
  const int b = gid & 7;
  const int mt_ = (gid >> 3) & 7;
  const int ot_ = (gid >> 6) & 1;
  const int h = gid >> 7;
  const int hb = h * B_ + b;
  const int m0 = mt_ * 128, o0 = ot_ * 128;
  const int t = threadIdx.x, w = t >> 6, lane = t & 63;
  const int col = lane & 15, quad = lane >> 4;

  const int srow = t >> 3;                       // 0..31
  const int sseg = (t & 7) ^ (srow & 7);
  const unsigned short* agp = xb + (size_t)(b * N_ + m0 + srow) * FIN + sseg * 8;
  const unsigned short* bgp = Wb + (size_t)(h * FOUT + o0 + srow) * FIN + sseg * 8;

  f32x4 acc[2][8];
  const f32x4 z4 = {0.f, 0.f, 0.f, 0.f};
#pragma unroll
  for (int mt = 0; mt < 2; ++mt)
#pragma unroll
    for (int ot = 0; ot < 8; ++ot) acc[mt][ot] = z4;

  for (int it = 0; it < FIN / 64; ++it) {
    __syncthreads();   // WAR: all waves done reading previous chunk
    const int k0 = it * 64;
#pragma unroll
    for (int i2 = 0; i2 < 4; ++i2) {
      gload16(agp + (size_t)i2 * 32 * FIN + k0, &As[i2 * 2048 + t * 8]);
      gload16(bgp + (size_t)i2 * 32 * FIN + k0, &Bs[i2 * 2048 + t * 8]);
    }
    __syncthreads();   // compiler drains vmcnt(0) before barrier -> data ready

#pragma unroll
    for (int kb = 0; kb < 2; ++kb) {
      s16x8 af[2], bf[8];
#pragma unroll
      for (int mt = 0; mt < 2; ++mt) {
        const int row = w * 32 + mt * 16 + col;
        af[mt] = *(const s16x8*)&As[row * 64 + ((kb * 4 + quad) ^ (row & 7)) * 8];
      }
#pragma unroll
      for (int ot = 0; ot < 8; ++ot) {
        const int row = ot * 16 + col;
        bf[ot] = *(const s16x8*)&Bs[row * 64 + ((kb * 4 + quad) ^ (row & 7)) * 8];
      }
#pragma unroll
      for (int mt = 0; mt < 2; ++mt)
#pragma unroll
        for (int ot = 0; ot < 8; ++ot)
          acc[mt][ot] = __builtin_amdgcn_mfma_f32_16x16x32_bf16(af[mt], bf[ot],
                                                                acc[mt][ot], 0, 0, 0);
    }
  }

  const int kkw = (m0 >> 5) + w;
  float pf1[2][4] = {{0.f}}, pf2[2][4] = {{0.f}};
#pragma unroll
  for (int mt = 0; mt < 2; ++mt) {
#pragma unroll
    for (int ot = 0; ot < 8; ++ot) {
      const int o = o0 + ot * 16 + col;
      const float va1 = a1[h * FOUT + o], va2 = a2[h * FOUT + o];
      const int otg = (o0 >> 4) + ot;
      unsigned char* fb =
          htq + (((size_t)(hb * 16 + otg) * 32 + kkw) << 9);
      const unsigned int q =
          pk4_fp8(acc[mt][ot][0], acc[mt][ot][1], acc[mt][ot][2], acc[mt][ot][3]);
      *(unsigned int*)(fb + (2 * mt + (quad >> 1)) * 128 + col * 8 +
                       (quad & 1) * 4) = q;
#pragma unroll
      for (int r = 0; r < 4; ++r) {
        pf1[mt][r] += acc[mt][ot][r] * va1;
        pf2[mt][r] += acc[mt][ot][r] * va2;
      }
    }
  }
#pragma unroll
  for (int off = 1; off <= 8; off <<= 1)
#pragma unroll
    for (int mt = 0; mt < 2; ++mt)
#pragma unroll
      for (int r = 0; r < 4; ++r) {
        pf1[mt][r] += __shfl_xor(pf1[mt][r], off);
        pf2[mt][r] += __shfl_xor(pf2[mt][r], off);
      }
  if (col == 0) {
#pragma unroll
    for (int mt = 0; mt < 2; ++mt)
#pragma unroll
      for (int r = 0; r < 4; ++r) {
        const int n = m0 + w * 32 + mt * 16 + quad * 4 + r;
        atomicAdd(&f1[hb * N_ + n], pf1[mt][r]);
        atomicAdd(&f2[hb * N_ + n], pf2[mt][r]);
      }
  }
}

// ---------------------------------------------------------------------------
// Kernel 2: pv — fused weight-gen + fp8 MFMA GEMM. R19: the gen->MFMA serial
// dependency is broken by a one-chunk SOFTWARE PIPELINE on the generated
// operands: during phase c's MFMAs (consuming Acur, generated last phase)
// the wave issues the VALU/trans gen of chunk c+1 into the parity set Anxt.
// The streams are independent -> matrix pipe and VALU/trans pipe overlap
// within each wave (R17 alternated them serially: 81 us, MfmaUtil 17%).
// adj dwords preloaded in prologue (16 VGPR) so the only in-flight vmem at
// each barrier is the 4 stage loads (vmcnt(0) issued a full phase earlier).
// Block = 1 head, 128 rows x 128 cols, 256 thr = 4 row-waves, grid 1024 =
// 8b(XCD) x 2oc x 8h x 8it; launch_bounds(256,3) for the parity-set regs.
// ---------------------------------------------------------------------------
__global__ __launch_bounds__(256, 3) void pv(
    const unsigned char* __restrict__ htq, const float* __restrict__ f1,
    const float* __restrict__ f2, const unsigned int* __restrict__ adjP,
    float* __restrict__ pp) {
  __shared__ __align__(16) unsigned char Bsh[2][16384];  // [buf][otgl*2048+kkl*512]
  __shared__ __align__(16) float f2sh[N_];               // 4 KB, this head's f2
  const int id = blockIdx.x;
  const int b = id & 7;                // XCD-keyed
  const int oc = (id >> 3) & 1;        // col half: otg in [oc*8, +8)
  const int h = (id >> 4) & 7;         // single head
  const int it = id >> 7;              // 0..7 (128-row groups)
  const int tid = threadIdx.x;
  const int w = tid >> 6, lane = tid & 63;
  const int col = lane & 15, quad = lane >> 4;
  const int rb = it * 8 + w * 2;       // this wave's rows [rb*16, rb*16+32)

  const int hb = h * B_ + b;
  const unsigned char* bp = htq + (((size_t)(hb * 16 + oc * 8) * 32) << 9);
  const int row0 = rb * 16 + col;
  const int row1 = row0 + 16;
  const unsigned int* adp0 = adjP + ((size_t)(b * N_ + row0) << 5) + quad * 8;
  const unsigned int* adp1 = adjP + ((size_t)(b * N_ + row1) << 5) + quad * 8;

  // stage: 4 x gload16 per thread covers the 16 KB chunk (8 otgl x 2 KB).
#define STAGE(buf, c)                                                        \
  {                                                                          \
    _Pragma("unroll")                                                        \
    for (int i = 0; i < 4; ++i) {                                            \
      const int flat = i * 4096 + tid * 16;                                  \
      gload16(bp + (size_t)(flat >> 11) * 16384 + (c) * 2048 + (flat & 2047),\
              &Bsh[buf][flat]);                                              \
    }                                                                        \
  }

  f32x4 acc[2][8];
  const f32x4 z4 = {0.f, 0.f, 0.f, 0.f};
#pragma unroll
  for (int g = 0; g < 2; ++g)
#pragma unroll
    for (int t = 0; t < 8; ++t) acc[g][t] = z4;

  // ---- prologue: f2 -> LDS, adj preload (all 8 chunks), m2/f1/mhat,
  //      stage chunk0, then gen chunk0 -> Ae (after the barrier).
  const float* f2r = f2 + (size_t)hb * N_;
  gload16(f2r + tid * 4, &f2sh[tid * 4]);
  STAGE(0, 0)
  const uint4 av00 = *(const uint4*)(adp0);      // row0 chunks 0..3
  const uint4 av01 = *(const uint4*)(adp0 + 4);  // row0 chunks 4..7
  const uint4 av10 = *(const uint4*)(adp1);      // row1 chunks 0..3
  const uint4 av11 = *(const uint4*)(adp1 + 4);  // row1 chunks 4..7
  unsigned int a0[8], a1[8];
  a0[0] = av00.x; a0[1] = av00.y; a0[2] = av00.z; a0[3] = av00.w;
  a0[4] = av01.x; a0[5] = av01.y; a0[6] = av01.z; a0[7] = av01.w;
  a1[0] = av10.x; a1[1] = av10.y; a1[2] = av10.z; a1[3] = av10.w;
  a1[4] = av11.x; a1[5] = av11.y; a1[6] = av11.z; a1[7] = av11.w;
  float m2 = -3.0e38f;
#pragma unroll
  for (int c = 0; c < 16; ++c) m2 = fmaxf(m2, f2r[lane + c * 64]);
#pragma unroll
  for (int off = 32; off; off >>= 1) m2 = fmaxf(m2, __shfl_xor(m2, off));
  const float f1a = f1[(size_t)hb * N_ + row0];
  const float f1b = f1[(size_t)hb * N_ + row1];
  const float tb0 = f1a + m2, tb1 = f1b + m2;
  const float mh0 = fmaxf(tb0, ALPHA * tb0);   // >= leaky(f1a+f2j) for all j
  const float mh1 = fmaxf(tb1, ALPHA * tb1);
  float dsum0 = 0.f, dsum1 = 0.f;
  asm volatile("s_waitcnt vmcnt(0)" ::: "memory");  // f2sh + stage0 + adj done
  __builtin_amdgcn_s_barrier();                     // f2sh visible block-wide

  long Ae[8], Ao[8];
#pragma unroll
  for (int kkl = 0; kkl < 4; ++kkl) {              // gen chunk 0 -> Ae
    const float4 fA = *(const float4*)&f2sh[kkl * 32 + quad * 8];
    const float4 fB = *(const float4*)&f2sh[kkl * 32 + quad * 8 + 4];
    Ae[kkl] = gen8((a0[0] >> (kkl * 8)) & 0xFFu, fA, fB, f1a, mh0, dsum0);
    Ae[4 + kkl] = gen8((a1[0] >> (kkl * 8)) & 0xFFu, fA, fB, f1b, mh1, dsum1);
  }

#define PHASE(c, Acur, Anxt)                                                 \
  {                                                                          \
    if ((c) < 7) STAGE(1 - ((c) & 1), (c) + 1)                               \
    _Pragma("unroll")                                                        \
    for (int kkl = 0; kkl < 4; ++kkl) {                                      \
      if ((c) < 7) { /* gen chunk c+1 into parity set: independent of the */ \
        const int kk = ((c) + 1) * 4 + kkl;      /* MFMAs below -> overlap */\
        const float4 fA = *(const float4*)&f2sh[kk * 32 + quad * 8];         \
        const float4 fB = *(const float4*)&f2sh[kk * 32 + quad * 8 + 4];     \
        Anxt[kkl] =                                                          \
            gen8((a0[(c) + 1] >> (kkl * 8)) & 0xFFu, fA, fB, f1a, mh0, dsum0); \
        Anxt[4 + kkl] =                                                      \
            gen8((a1[(c) + 1] >> (kkl * 8)) & 0xFFu, fA, fB, f1b, mh1, dsum1); \
      }                                                                      \
      const unsigned char* bl_ = &Bsh[(c) & 1][kkl * 512 + lane * 8];        \
      __builtin_amdgcn_s_setprio(1);                                         \
      _Pragma("unroll")                                                      \
      for (int t = 0; t < 8; ++t) {                                          \
        const long bf = *(const long*)(bl_ + t * 2048);                      \
        acc[0][t] = __builtin_amdgcn_mfma_f32_16x16x32_fp8_fp8(Acur[kkl], bf, acc[0][t], 0, 0, 0); \
        acc[1][t] = __builtin_amdgcn_mfma_f32_16x16x32_fp8_fp8(Acur[4 + kkl], bf, acc[1][t], 0, 0, 0); \
      }                                                                      \
      __builtin_amdgcn_s_setprio(0);                                         \
    }                                                                        \
    if ((c) < 7) {                                                           \
      asm volatile("s_waitcnt vmcnt(0)" ::: "memory"); /* only stage loads */\
      __builtin_amdgcn_s_barrier();                                          \
    }                                                                        \
  }

  PHASE(0, Ae, Ao)
  PHASE(1, Ao, Ae)
  PHASE(2, Ae, Ao)
  PHASE(3, Ao, Ae)
  PHASE(4, Ae, Ao)
  PHASE(5, Ao, Ae)
  PHASE(6, Ae, Ao)
  PHASE(7, Ao, Ae)
#undef PHASE
#undef STAGE

  // ---- exact full-row denominators: quad-slices -> full sum per col
  dsum0 += __shfl_xor(dsum0, 16);
  dsum0 += __shfl_xor(dsum0, 32);
  dsum1 += __shfl_xor(dsum1, 16);
  dsum1 += __shfl_xor(dsum1, 32);

  // ---- normalize, ELU, write single-head partial
  float* pdst = pp + (size_t)h * ((size_t)B_ * N_ * FOUT);
#pragma unroll
  for (int g = 0; g < 2; ++g)
#pragma unroll
    for (int r = 0; r < 4; ++r) {
      const float den = __shfl(g == 0 ? dsum0 : dsum1, quad * 4 + r);
      const float inv = 1.0f / den;
      const int orow = (rb + g) * 16 + quad * 4 + r;
#pragma unroll
      for (int t = 0; t < 8; ++t) {
        const float oh = acc[g][t][r] * inv;
        pdst[(size_t)(b * N_ + orow) * FOUT + oc * 128 + t * 16 + col] =
            oh > 0.f ? oh : __expf(oh) - 1.f;
      }
    }
}

// ---------------------------------------------------------------------------
// Kernel 3: sum 8 single-head partials + log_softmax over o. Wave per row.
// ---------------------------------------------------------------------------
__global__ __launch_bounds__(256) void logsm(
    const float* __restrict__ pp, float* __restrict__ out) {
  const int row = blockIdx.x * 4 + (threadIdx.x >> 6);
  const int lane = threadIdx.x & 63;
  const size_t base = (size_t)row * FOUT;
  const size_t PSZ = (size_t)B_ * N_ * FOUT;
  float v[4];
  float m = -3.0e38f;
#pragma unroll
  for (int c = 0; c < 4; ++c) {
    const size_t idx = base + c * 64 + lane;
    float s = 0.f;
#pragma unroll
    for (int hh = 0; hh < 8; ++hh) s += pp[hh * PSZ + idx];
    v[c] = s;
    m = fmaxf(m, v[c]);
  }
#pragma unroll
  for (int off = 32; off; off >>= 1) m = fmaxf(m, __shfl_xor(m, off));
  float s = 0.f;
#pragma unroll
  for (int c = 0; c < 4; ++c) s += __expf(v[c] - m);
#pragma unroll
  for (int off = 32; off; off >>= 1) s += __shfl_xor(s, off);
  const float lg = m + logf(s);
#pragma unroll
  for (int c = 0; c < 4; ++c)
    out[base + c * 64 + lane] = v[c] - lg;
}

// ---------------------------------------------------------------------------
extern "C" void kernel_launch(void* const* d_in, const int* in_sizes, int n_in,
                              void* d_out, int out_size, void* d_ws,
                              size_t ws_size, hipStream_t stream) {
  const float* x   = (const float*)d_in[0];
  const int*   adj = (const int*)d_in[1];
  const float* W   = (const float*)d_in[2];
  const float* a1  = (const float*)d_in[3];
  const float* a2  = (const float*)d_in[4];
  float* out = (float*)d_out;

  unsigned char* htq = (unsigned char*)d_ws;                          // 16 MB fp8 h (frag)
  unsigned short* xb = (unsigned short*)(htq + (size_t)H_ * B_ * FOUT * N_); // 8 MB
  unsigned short* Wb = xb + (size_t)XT;                               // 2 MB
  float* f1 = (float*)(Wb + (size_t)WT);                              // 256 KB
  float* f2 = f1 + (size_t)H_ * B_ * N_;                              // 256 KB
  float* pad = f2 + (size_t)H_ * B_ * N_;                             // 256 KB (unused)
  float* part2 = pad + (size_t)H_ * B_ * N_;                          // 8 MB (unused)
  float* part3 = part2 + (size_t)B_ * N_ * FOUT;                      // 8 MB (unused)
  unsigned int* adjP = (unsigned int*)(part3 + (size_t)B_ * N_ * FOUT); // 1 MB
  float* pp = (float*)(adjP + (size_t)B_ * N_ * 32);  // 64 MB: 8 head partials

  prep<<<CVB + ZRB + PKB, 256, 0, stream>>>(x, W, adj, xb, Wb, f1, adjP);

  proj_mfma<<<1024, 256, 0, stream>>>(xb, Wb, a1, a2, htq, f1, f2);

  pv<<<1024, 256, 0, stream>>>(htq, f1, f2, adjP, pp);

  logsm<<<(B_ * N_) / 4, 256, 0, stream>>>(pp, out);
}

// Round 10
// 190.413 us; speedup vs baseline: 1.1266x; 1.0687x over previous
//
#include <hip/hip_runtime.h>
#include <math.h>

#define B_    8
#define N_    1024
#define FIN   512
#define FOUT  256
#define H_    8
#define ALPHA 0.2f

#define XT (B_ * N_ * FIN)     // 4194304 x elements
#define WT (H_ * FOUT * FIN)   // 1048576 W elements

typedef short s16x8 __attribute__((ext_vector_type(8)));
typedef float f32x4 __attribute__((ext_vector_type(4)));

__device__ __forceinline__ unsigned short f2bf(float f) {
  unsigned int u = __float_as_uint(f);
  u = (u + 0x7FFFu + ((u >> 16) & 1u)) >> 16;   // round-to-nearest-even
  return (unsigned short)u;
}

// pack 4 fp32 -> 4 OCP e4m3 bytes (v_cvt_pk_fp8_f32; OCP format on gfx950)
__device__ __forceinline__ unsigned int pk4_fp8(float a, float b, float c,
                                                float d) {
  int u = __builtin_amdgcn_cvt_pk_fp8_f32(a, b, 0, false);   // bytes 0,1
  u = __builtin_amdgcn_cvt_pk_fp8_f32(c, d, u, true);        // bytes 2,3
  return (unsigned int)u;
}

// Exact dequant-sum of 4 packed e4m3 bytes (matches what an MFMA-with-ones
// column would accumulate, up to fp32 add order).
#if __has_builtin(__builtin_amdgcn_cvt_pk_f32_fp8)
#define HAVE_DEQ4 1
__device__ __forceinline__ float deq4(unsigned int u) {
  const auto a = __builtin_amdgcn_cvt_pk_f32_fp8((int)u, false);
  const auto b = __builtin_amdgcn_cvt_pk_f32_fp8((int)u, true);
  return (a[0] + a[1]) + (b[0] + b[1]);
}
#else
#define HAVE_DEQ4 0
// Emulated e4m3 quantize (RNE); p is known to be in [0,1].
__device__ __forceinline__ float q8e4m3(float p) {
  if (p >= 0.015625f) {                      // normal range: 3 mantissa bits
    unsigned int u = __float_as_uint(p);
    u = (u + 0x7FFFFu + ((u >> 20) & 1u)) & 0xFFF00000u;
    return __uint_as_float(u);
  }
  return (p + 16384.f) - 16384.f;            // subnormal: snap to 2^-9 grid
}
#endif

// async global->LDS, 16 B per lane (global_load_lds_dwordx4)
__device__ __forceinline__ void gload16(const void* g, void* l) {
  __builtin_amdgcn_global_load_lds(
      (const __attribute__((address_space(1))) unsigned int*)g,
      (__attribute__((address_space(3))) unsigned int*)l, 16, 0, 0);
}

// ---------------------------------------------------------------------------
// Fragment layouts (lane-linear, 512 B per (tile,kk) block):
//  htq (B-operand): block ((hb*16 + otg)*32 + kk), byte quad*128+col*8+j =
//      h[hb][k=kk*32+quad*8+j][o=otg*16+col]
//  wq  (A-operand): block ((hb*64 + rb)*32 + kk), byte quad*128+col*8+j =
//      softmax-weight[row=rb*16+col][k=kk*32+quad*8+j]
// A wave's load/store is base + lane*8: one coalesced 512 B access.
// ---------------------------------------------------------------------------

// ---------------------------------------------------------------------------
// Kernel 0: fp32->bf16 convert of x,W + zero f1/f2/dnm + byte-transposed adj
// pack. adjP per row (128 B): byte [q*32 + kk] = adj bits j = kk*32+q*8 ..+7
// ---------------------------------------------------------------------------
#define CVB  ((XT + WT) / 1024)          // 5120 convert blocks
#define ZRB  192                         // zero blocks: f1,f2,dnm (768 KB)
#define PKB  ((B_ * N_ * 32) / 256)      // 1024 adj-pack blocks

__global__ __launch_bounds__(256) void prep(
    const float* __restrict__ x, const float* __restrict__ W,
    const int* __restrict__ adj, unsigned short* __restrict__ xb,
    unsigned short* __restrict__ Wb, float* __restrict__ f12,
    unsigned int* __restrict__ adjP) {
  const int blk = blockIdx.x;
  if (blk >= CVB + ZRB) {    // ---- pack adj (byte-transposed) ----
    const int dw = (blk - CVB - ZRB) * 256 + threadIdx.x;  // permuted dword
    const int r = dw >> 5, pd = dw & 31;
    const int q = pd >> 3, c8 = pd & 7;                    // c8 = kk>>2
    const int* ap = adj + (size_t)r * N_;
    unsigned int out = 0;
#pragma unroll
    for (int i = 0; i < 4; ++i) {        // byte i: kk = c8*4+i
      const int jb = (c8 * 4 + i) * 32 + q * 8;
      int4 v0 = *(const int4*)(ap + jb);
      int4 v1 = *(const int4*)(ap + jb + 4);
      unsigned int byte = 0;
      byte |= (v0.x ? 1u : 0u) << 0; byte |= (v0.y ? 1u : 0u) << 1;
      byte |= (v0.z ? 1u : 0u) << 2; byte |= (v0.w ? 1u : 0u) << 3;
      byte |= (v1.x ? 1u : 0u) << 4; byte |= (v1.y ? 1u : 0u) << 5;
      byte |= (v1.z ? 1u : 0u) << 6; byte |= (v1.w ? 1u : 0u) << 7;
      out |= byte << (i * 8);
    }
    adjP[dw] = out;
    return;
  }
  if (blk >= CVB) {          // ---- zero f1/f2/dnm (contiguous) ----
    const int i = (blk - CVB) * 256 + threadIdx.x;
    ((float4*)f12)[i] = make_float4(0.f, 0.f, 0.f, 0.f);
    return;
  }
  // ---- fp32 -> bf16 ----
  const int i = (blk * 256 + threadIdx.x) * 4;
  const float* src;
  unsigned short* dst;
  int off;
  if (i < XT) { src = x; dst = xb; off = i; }
  else        { src = W; dst = Wb; off = i - XT; }
  float4 v = *(const float4*)(src + off);
  ushort4 s;
  s.x = f2bf(v.x); s.y = f2bf(v.y); s.z = f2bf(v.z); s.w = f2bf(v.w);
  *(ushort4*)(dst + off) = s;
}

// ---------------------------------------------------------------------------
// Kernel 1: projection GEMM: global_load_lds width=16 staging with
// pre-swizzled source, 128x128 tile, grid 1024.
// ---------------------------------------------------------------------------
__global__ __launch_bounds__(256, 3) void proj_mfma(
    const unsigned short* __restrict__ xb, const unsigned short* __restrict__ Wb,
    const float* __restrict__ a1, const float* __restrict__ a2,
    unsigned char* __restrict__ htq, float* __restrict__ f1,
    float* __restrict__ f2) {
  __shared__ __align__(16) unsigned short As[128 * 64];  // 16 KB
  __shared__ __align__(16) unsigned short Bs[128 * 64];  // 16 KB
  const int gid = blockIdx.x;
  const int b = gid & 7;
  const int mt_ = (gid >> 3) & 7;
  const int ot_ = (gid >> 6) & 1;
  const int h = gid >> 7;
  const int hb = h * B_ + b;
  const int m0 = mt_ * 128, o0 = ot_ * 128;
  const int t = threadIdx.x, w = t >> 6, lane = t & 63;
  const int col = lane & 15, quad = lane >> 4;

  const int srow = t >> 3;                       // 0..31
  const int sseg = (t & 7) ^ (srow & 7);
  const unsigned short* agp = xb + (size_t)(b * N_ + m0 + srow) * FIN + sseg * 8;
  const unsigned short* bgp = Wb + (size_t)(h * FOUT + o0 + srow) * FIN + sseg * 8;

  f32x4 acc[2][8];
  const f32x4 z4 = {0.f, 0.f, 0.f, 0.f};
#pragma unroll
  for (int mt = 0; mt < 2; ++mt)
#pragma unroll
    for (int ot = 0; ot < 8; ++ot) acc[mt][ot] = z4;

  for (int it = 0; it < FIN / 64; ++it) {
    __syncthreads();   // WAR: all waves done reading previous chunk
    const int k0 = it * 64;
#pragma unroll
    for (int i2 = 0; i2 < 4; ++i2) {
      gload16(agp + (size_t)i2 * 32 * FIN + k0, &As[i2 * 2048 + t * 8]);
      gload16(bgp + (size_t)i2 * 32 * FIN + k0, &Bs[i2 * 2048 + t * 8]);
    }
    __syncthreads();   // compiler drains vmcnt(0) before barrier -> data ready

#pragma unroll
    for (int kb = 0; kb < 2; ++kb) {
      s16x8 af[2], bf[8];
#pragma unroll
      for (int mt = 0; mt < 2; ++mt) {
        const int row = w * 32 + mt * 16 + col;
        af[mt] = *(const s16x8*)&As[row * 64 + ((kb * 4 + quad) ^ (row & 7)) * 8];
      }
#pragma unroll
      for (int ot = 0; ot < 8; ++ot) {
        const int row = ot * 16 + col;
        bf[ot] = *(const s16x8*)&Bs[row * 64 + ((kb * 4 + quad) ^ (row & 7)) * 8];
      }
#pragma unroll
      for (int mt = 0; mt < 2; ++mt)
#pragma unroll
        for (int ot = 0; ot < 8; ++ot)
          acc[mt][ot] = __builtin_amdgcn_mfma_f32_16x16x32_bf16(af[mt], bf[ot],
                                                                acc[mt][ot], 0, 0, 0);
    }
  }

  const int kkw = (m0 >> 5) + w;
  float pf1[2][4] = {{0.f}}, pf2[2][4] = {{0.f}};
#pragma unroll
  for (int mt = 0; mt < 2; ++mt) {
#pragma unroll
    for (int ot = 0; ot < 8; ++ot) {
      const int o = o0 + ot * 16 + col;
      const float va1 = a1[h * FOUT + o], va2 = a2[h * FOUT + o];
      const int otg = (o0 >> 4) + ot;
      unsigned char* fb =
          htq + (((size_t)(hb * 16 + otg) * 32 + kkw) << 9);
      const unsigned int q =
          pk4_fp8(acc[mt][ot][0], acc[mt][ot][1], acc[mt][ot][2], acc[mt][ot][3]);
      *(unsigned int*)(fb + (2 * mt + (quad >> 1)) * 128 + col * 8 +
                       (quad & 1) * 4) = q;
#pragma unroll
      for (int r = 0; r < 4; ++r) {
        pf1[mt][r] += acc[mt][ot][r] * va1;
        pf2[mt][r] += acc[mt][ot][r] * va2;
      }
    }
  }
#pragma unroll
  for (int off = 1; off <= 8; off <<= 1)
#pragma unroll
    for (int mt = 0; mt < 2; ++mt)
#pragma unroll
      for (int r = 0; r < 4; ++r) {
        pf1[mt][r] += __shfl_xor(pf1[mt][r], off);
        pf2[mt][r] += __shfl_xor(pf2[mt][r], off);
      }
  if (col == 0) {
#pragma unroll
    for (int mt = 0; mt < 2; ++mt)
#pragma unroll
      for (int r = 0; r < 4; ++r) {
        const int n = m0 + w * 32 + mt * 16 + quad * 4 + r;
        atomicAdd(&f1[hb * N_ + n], pf1[mt][r]);
        atomicAdd(&f2[hb * N_ + n], pf2[mt][r]);
      }
  }
}

// ---------------------------------------------------------------------------
// Kernel 2: wgen — softmax weights -> fp8, written in A-fragment layout,
// plus exact row-sum of the quantized weights into dnm[hb][row].
// ---------------------------------------------------------------------------
__global__ __launch_bounds__(256) void wgen(
    const float* __restrict__ f1, const float* __restrict__ f2,
    const unsigned int* __restrict__ adjP, unsigned char* __restrict__ wq,
    float* __restrict__ dnm) {
  const int id = blockIdx.x;
  const int b = id & 7, h = (id >> 3) & 7;
  const int rbg = (id >> 6) & 15;
  const int kkh = id >> 10;            // kk half: [kkh*16, +16)
  const int w = threadIdx.x >> 6, lane = threadIdx.x & 63;
  const int col = lane & 15, quad = lane >> 4;
  const int hb = h * B_ + b;
  const int rb = rbg * 4 + w;
  const int row = rb * 16 + col;

  // per-wave M2 = max_j f2[hb][j]
  const float* f2r = f2 + (size_t)hb * N_;
  float m2 = -3.0e38f;
#pragma unroll
  for (int c = 0; c < 16; ++c) m2 = fmaxf(m2, f2r[lane + c * 64]);
#pragma unroll
  for (int off = 32; off; off >>= 1) m2 = fmaxf(m2, __shfl_xor(m2, off));

  const float f1i = f1[(size_t)hb * N_ + row];
  const float tb = f1i + m2;
  const float mhat = fmaxf(tb, ALPHA * tb);   // >= leaky(f1i+f2j) for all j

  const unsigned int* adp = adjP + ((size_t)(b * N_ + row) << 5) + quad * 8;
  const float* f2p = f2r + quad * 8;
  unsigned char* wp = wq + (((size_t)(hb * 64 + rb) * 32) << 9) + lane * 8;

  float dsum = 0.f;
#pragma unroll
  for (int k4i = 0; k4i < 4; ++k4i) {
    const int k4 = kkh * 4 + k4i;
    const unsigned int ad = adp[k4];
#pragma unroll
    for (int k2 = 0; k2 < 4; ++k2) {
      const int kk = k4 * 4 + k2;
      const unsigned int ab = (ad >> (k2 * 8)) & 0xFFu;
      const float4 fA = *(const float4*)(f2p + kk * 32);
      const float4 fB = *(const float4*)(f2p + kk * 32 + 4);
      float ex[8];
#pragma unroll
      for (int j = 0; j < 8; ++j) {
        const float fv = j < 4 ? ((const float*)&fA)[j]
                               : ((const float*)&fB)[j - 4];
        const float tt = f1i + fv;
        const float l = fmaxf(tt, ALPHA * tt);
        const float p = __expf(l - mhat);
        ex[j] = ((ab >> j) & 1u) ? p : 0.f;
      }
      const unsigned int lo = pk4_fp8(ex[0], ex[1], ex[2], ex[3]);
      const unsigned int hi = pk4_fp8(ex[4], ex[5], ex[6], ex[7]);
#if HAVE_DEQ4
      dsum += deq4(lo) + deq4(hi);
#else
#pragma unroll
      for (int j = 0; j < 8; ++j) dsum += q8e4m3(ex[j]);
#endif
      *(uint2*)(wp + kk * 512) = make_uint2(lo, hi);
    }
  }
  // reduce this half's row-sum across the 4 quads (lanes col, col+16, +32, +48)
  dsum += __shfl_xor(dsum, 16);
  dsum += __shfl_xor(dsum, 32);
  if (quad == 0) atomicAdd(&dnm[(size_t)hb * N_ + row], dsum);
}

// ---------------------------------------------------------------------------
// Kernel 3: pv — fp8 MFMA GEMM, wave = 32 rows x 64 cols x 2 heads.
// 16-phase fully-unrolled pipeline (chunk = 4 kk). Per phase:
//   stage next B-chunk (2 x global_load_lds) || prefetch next A-chunk into
//   the parity register set (8 loads) -> 16 ds_read_b64 + 32 MFMA (setprio)
//   -> s_waitcnt vmcnt(8) + RAW s_barrier.
// The counted vmcnt retires stage(+den) loads before the barrier (cross-wave
// LDS visibility) while the 8 A-prefetch loads stay in flight ACROSS it.
// ---------------------------------------------------------------------------
__global__ __launch_bounds__(256) void pv(
    const unsigned char* __restrict__ htq, const unsigned char* __restrict__ wq,
    const float* __restrict__ dnm, float* __restrict__ p0,
    float* __restrict__ p1, float* __restrict__ p2, float* __restrict__ p3) {
  __shared__ __align__(16) unsigned char Bsh[2][8192];  // [buf][otg*2048+kkl*512]
  const int id = blockIdx.x;
  const int b = id & 7;                // XCD-keyed
  const int g0 = (id >> 3) & 3;        // heads {2g0, 2g0+1}
  const int oq = (id >> 5) & 3;        // o-quarter: otg in [oq*4, +4)
  const int it = id >> 7;              // 0..7 (128-row groups)
  const int tid = threadIdx.x;
  const int w = tid >> 6, lane = tid & 63;
  const int col = lane & 15, quad = lane >> 4;
  const int rb = it * 8 + w * 2;       // this wave's rows [rb*16, rb*16+32)

  const int hb0 = (g0 * 2 + 0) * B_ + b;
  const int hb1 = (g0 * 2 + 1) * B_ + b;
  const unsigned char* ap0 =
      wq + (((size_t)(hb0 * 64 + rb) * 32) << 9) + lane * 8;
  const unsigned char* ap1 =
      wq + (((size_t)(hb1 * 64 + rb) * 32) << 9) + lane * 8;
  const unsigned char* bp0 = htq + (((size_t)(hb0 * 16 + oq * 4) * 32) << 9);
  const unsigned char* bp1 = htq + (((size_t)(hb1 * 16 + oq * 4) * 32) << 9);

  // stage geometry: 2 x 16B per thread covers the 8 KB chunk.
  // flat = otg*2048 + kkl*512 + byte ; global = bp + otg*16384 + c*2048 + rest
  const int flat0 = tid * 16, flat1 = 4096 + tid * 16;
  const int gs0 = (flat0 >> 11) * 16384 + (flat0 & 2047);
  const int gs1 = (flat1 >> 11) * 16384 + (flat1 & 2047);

  float hsum[2][4][4];
#pragma unroll
  for (int g = 0; g < 2; ++g)
#pragma unroll
    for (int t = 0; t < 4; ++t)
#pragma unroll
      for (int r = 0; r < 4; ++r) hsum[g][t][r] = 0.f;

  f32x4 acc[2][4];
  const f32x4 z4 = {0.f, 0.f, 0.f, 0.f};
  float4 den0, den1;
  long Ae[8], Ao[8];

  // ---- prologue: head0 den, stage chunk0 -> buf0, A(chunk0) -> Ae
  {
    const float* dr = dnm + (size_t)hb0 * N_ + quad * 4;
    den0 = *(const float4*)(dr + (rb + 0) * 16);
    den1 = *(const float4*)(dr + (rb + 1) * 16);
  }
  gload16(bp0 + gs0, &Bsh[0][flat0]);
  gload16(bp0 + gs1, &Bsh[0][flat1]);
#pragma unroll
  for (int k = 0; k < 4; ++k) {
    Ae[k] = *(const long*)(ap0 + k * 512);
    Ae[4 + k] = *(const long*)(ap0 + 16384 + k * 512);
  }
  asm volatile("s_waitcnt vmcnt(8)" ::: "memory");  // den+stage done; Ae flies
  __builtin_amdgcn_s_barrier();

#define PHASE(cc, Acur, Anxt)                                                \
  {                                                                          \
    const int c_ = (cc) & 7;                                                 \
    const int cur_ = (cc) & 1;                                               \
    if ((cc) == 8) { /* head1 denominators (oldest vmem this phase) */       \
      const float* dr_ = dnm + (size_t)hb1 * N_ + quad * 4;                  \
      den0 = *(const float4*)(dr_ + (rb + 0) * 16);                          \
      den1 = *(const float4*)(dr_ + (rb + 1) * 16);                          \
    }                                                                        \
    if ((cc) < 15) {                                                         \
      const int cn_ = (cc) + 1;                                              \
      const unsigned char* gb_ = (cn_ >= 8) ? bp1 : bp0;                     \
      const int co_ = (cn_ & 7) * 2048;                                      \
      gload16(gb_ + gs0 + co_, &Bsh[1 - cur_][flat0]);                       \
      gload16(gb_ + gs1 + co_, &Bsh[1 - cur_][flat1]);                       \
      const unsigned char* an_ = (cn_ >= 8) ? ap1 : ap0;                     \
      const int ko_ = (cn_ & 7) * 2048;                                      \
      _Pragma("unroll")                                                      \
      for (int k = 0; k < 4; ++k) {                                          \
        Anxt[k] = *(const long*)(an_ + ko_ + k * 512);                       \
        Anxt[4 + k] = *(const long*)(an_ + 16384 + ko_ + k * 512);           \
      }                                                                      \
    }                                                                        \
    if (c_ == 0) {                                                           \
      _Pragma("unroll") for (int g = 0; g < 2; ++g)                          \
      _Pragma("unroll") for (int t = 0; t < 4; ++t) acc[g][t] = z4;          \
    }                                                                        \
    {                                                                        \
      const unsigned char* bl_ = &Bsh[cur_][lane * 8];                       \
      _Pragma("unroll")                                                      \
      for (int kkl = 0; kkl < 4; ++kkl) {                                    \
        const long b0_ = *(const long*)(bl_ + 0 * 2048 + kkl * 512);         \
        const long b1_ = *(const long*)(bl_ + 1 * 2048 + kkl * 512);         \
        const long b2_ = *(const long*)(bl_ + 2 * 2048 + kkl * 512);         \
        const long b3_ = *(const long*)(bl_ + 3 * 2048 + kkl * 512);         \
        __builtin_amdgcn_s_setprio(1);                                       \
        acc[0][0] = __builtin_amdgcn_mfma_f32_16x16x32_fp8_fp8(Acur[kkl], b0_, acc[0][0], 0, 0, 0); \
        acc[1][0] = __builtin_amdgcn_mfma_f32_16x16x32_fp8_fp8(Acur[4 + kkl], b0_, acc[1][0], 0, 0, 0); \
        acc[0][1] = __builtin_amdgcn_mfma_f32_16x16x32_fp8_fp8(Acur[kkl], b1_, acc[0][1], 0, 0, 0); \
        acc[1][1] = __builtin_amdgcn_mfma_f32_16x16x32_fp8_fp8(Acur[4 + kkl], b1_, acc[1][1], 0, 0, 0); \
        acc[0][2] = __builtin_amdgcn_mfma_f32_16x16x32_fp8_fp8(Acur[kkl], b2_, acc[0][2], 0, 0, 0); \
        acc[1][2] = __builtin_amdgcn_mfma_f32_16x16x32_fp8_fp8(Acur[4 + kkl], b2_, acc[1][2], 0, 0, 0); \
        acc[0][3] = __builtin_amdgcn_mfma_f32_16x16x32_fp8_fp8(Acur[kkl], b3_, acc[0][3], 0, 0, 0); \
        acc[1][3] = __builtin_amdgcn_mfma_f32_16x16x32_fp8_fp8(Acur[4 + kkl], b3_, acc[1][3], 0, 0, 0); \
        __builtin_amdgcn_s_setprio(0);                                       \
      }                                                                      \
    }                                                                        \
    if (c_ == 7) { /* end of head: normalize, ELU, head-sum */               \
      _Pragma("unroll") for (int g = 0; g < 2; ++g)                          \
      _Pragma("unroll") for (int r = 0; r < 4; ++r) {                        \
        const float dv_ = (g == 0) ? (&den0.x)[r] : (&den1.x)[r];            \
        const float inv_ = 1.0f / dv_;                                       \
        _Pragma("unroll") for (int t = 0; t < 4; ++t) {                      \
          const float oh_ = acc[g][t][r] * inv_;                             \
          hsum[g][t][r] += oh_ > 0.f ? oh_ : __expf(oh_) - 1.f;              \
        }                                                                    \
      }                                                                      \
    }                                                                        \
    if ((cc) < 15) {                                                         \
      asm volatile("s_waitcnt vmcnt(8)" ::: "memory"); /* stage done */      \
      __builtin_amdgcn_s_barrier();                    /* A-next flies */    \
    }                                                                        \
  }

  PHASE(0, Ae, Ao)  PHASE(1, Ao, Ae)  PHASE(2, Ae, Ao)  PHASE(3, Ao, Ae)
  PHASE(4, Ae, Ao)  PHASE(5, Ao, Ae)  PHASE(6, Ae, Ao)  PHASE(7, Ao, Ae)
  PHASE(8, Ae, Ao)  PHASE(9, Ao, Ae)  PHASE(10, Ae, Ao) PHASE(11, Ao, Ae)
  PHASE(12, Ae, Ao) PHASE(13, Ao, Ae) PHASE(14, Ae, Ao) PHASE(15, Ao, Ae)
#undef PHASE

  // ---- write head-pair partial: row (rb+g)*16+quad*4+r, col oq*64+t*16+col
  float* pdst = (g0 == 0) ? p0 : (g0 == 1) ? p1 : (g0 == 2) ? p2 : p3;
#pragma unroll
  for (int g = 0; g < 2; ++g)
#pragma unroll
    for (int t = 0; t < 4; ++t)
#pragma unroll
      for (int r = 0; r < 4; ++r) {
        const int orow = (rb + g) * 16 + quad * 4 + r;
        pdst[(size_t)(b * N_ + orow) * FOUT + oq * 64 + t * 16 + col] =
            hsum[g][t][r];
      }
}

// ---------------------------------------------------------------------------
// Kernel 4: sum 4 head-pair partials + log_softmax over o. Wave per row.
// ---------------------------------------------------------------------------
__global__ __launch_bounds__(256) void logsm(
    const float* __restrict__ p0, const float* __restrict__ p1,
    const float* __restrict__ p2, const float* __restrict__ p3,
    float* __restrict__ out) {
  const int row = blockIdx.x * 4 + (threadIdx.x >> 6);
  const int lane = threadIdx.x & 63;
  const size_t base = (size_t)row * FOUT;
  float v[4];
  float m = -3.0e38f;
#pragma unroll
  for (int c = 0; c < 4; ++c) {
    const size_t idx = base + c * 64 + lane;
    v[c] = p0[idx] + p1[idx] + p2[idx] + p3[idx];
    m = fmaxf(m, v[c]);
  }
#pragma unroll
  for (int off = 32; off; off >>= 1) m = fmaxf(m, __shfl_xor(m, off));
  float s = 0.f;
#pragma unroll
  for (int c = 0; c < 4; ++c) s += __expf(v[c] - m);
#pragma unroll
  for (int off = 32; off; off >>= 1) s += __shfl_xor(s, off);
  const float lg = m + logf(s);
#pragma unroll
  for (int c = 0; c < 4; ++c)
    out[base + c * 64 + lane] = v[c] - lg;
}

// ---------------------------------------------------------------------------
extern "C" void kernel_launch(void* const* d_in, const int* in_sizes, int n_in,
                              void* d_out, int out_size, void* d_ws,
                              size_t ws_size, hipStream_t stream) {
  const float* x   = (const float*)d_in[0];
  const int*   adj = (const int*)d_in[1];
  const float* W   = (const float*)d_in[2];
  const float* a1  = (const float*)d_in[3];
  const float* a2  = (const float*)d_in[4];
  float* out = (float*)d_out;

  unsigned char* htq = (unsigned char*)d_ws;                          // 16 MB fp8 h (frag)
  unsigned short* xb = (unsigned short*)(htq + (size_t)H_ * B_ * FOUT * N_); // 8 MB
  unsigned short* Wb = xb + (size_t)XT;                               // 2 MB
  float* f1 = (float*)(Wb + (size_t)WT);                              // 256 KB
  float* f2 = f1 + (size_t)H_ * B_ * N_;                              // 256 KB
  float* dnm = f2 + (size_t)H_ * B_ * N_;                             // 256 KB (zeroed w/ f1,f2)
  float* part2 = dnm + (size_t)H_ * B_ * N_;                          // 8 MB
  float* part3 = part2 + (size_t)B_ * N_ * FOUT;                      // 8 MB
  unsigned int* adjP = (unsigned int*)(part3 + (size_t)B_ * N_ * FOUT); // 1 MB
  unsigned char* wq = (unsigned char*)(adjP + (size_t)B_ * N_ * 32);  // 64 MB fp8 weights
  float* part1 = (float*)xb;   // xb dead after proj_mfma (8 MB reuse)

  prep<<<CVB + ZRB + PKB, 256, 0, stream>>>(x, W, adj, xb, Wb, f1, adjP);

  proj_mfma<<<1024, 256, 0, stream>>>(xb, Wb, a1, a2, htq, f1, f2);

  wgen<<<2048, 256, 0, stream>>>(f1, f2, adjP, wq, dnm);

  pv<<<1024, 256, 0, stream>>>(htq, wq, dnm, out, part1, part2, part3);

  logsm<<<(B_ * N_) / 4, 256, 0, stream>>>(out, part1, part2, part3, out);
}